// Round 6
// baseline (4566.827 us; speedup 1.0000x reference)
//
#include <hip/hip_runtime.h>
#include <math.h>

// GlimpseDecoder: B=512, N=T=200, D=128, H=8, dk=16
// R6: decode with ~10KB LDS -> 2 blocks/CU (4 waves/SIMD). Per-step q
// recomputed from global emb row vs persistent W_step regs; fixedc folded
// into step-invariant cbias; packed v_pk_fma_f32 dots; prescaled gk/lk.

#define Bsz 512
#define Nn  200
#define Dd  128
#define TANH_CLIP 10.0f
#define NEG_INF  -1e9f
#define LOG2E 1.4426950408889634f
#define LN2   0.6931471805599453f
#define QSCALE (0.25f * LOG2E)                      // 1/sqrt(16) * log2(e)
#define LSCALE (0.08838834764831845f * 2.0f * LOG2E) // 1/sqrt(128)*2*log2(e)

typedef float v2f __attribute__((ext_vector_type(2)));

__device__ __forceinline__ v2f pkfma(v2f a, v2f b, v2f c) {
    return __builtin_elementwise_fma(a, b, c);
}
__device__ __forceinline__ float rdlane(float v, int l) {
    union { float f; int i; } u; u.f = v;
    u.i = __builtin_amdgcn_readlane(u.i, l);
    return u.f;
}
__device__ __forceinline__ float fast_rcp(float x) {
    return __builtin_amdgcn_rcpf(x);
}
// dot of 16 floats via 8 v_pk_fma_f32 (two chains) + horizontal add
__device__ __forceinline__ float dot16pk(const float4* g4, const float4* q4) {
    const v2f* g = (const v2f*)g4;
    const v2f* q = (const v2f*)q4;
    v2f a0 = g[0] * q[0];
    v2f a1 = g[1] * q[1];
    a0 = pkfma(g[2], q[2], a0);
    a1 = pkfma(g[3], q[3], a1);
    a0 = pkfma(g[4], q[4], a0);
    a1 = pkfma(g[5], q[5], a1);
    a0 = pkfma(g[6], q[6], a0);
    a1 = pkfma(g[7], q[7], a1);
    const v2f a = a0 + a1;
    return a.x + a.y;
}

// ---------------- Kernel A: tiled proj = emb @ W_node -> gk*QS, gv, lk*LS ----
__global__ __launch_bounds__(256, 3) void proj_kernel(
    const float* __restrict__ emb, const float* __restrict__ Wn,
    float* __restrict__ gk, float* __restrict__ gv, float* __restrict__ lk)
{
    const int bid = blockIdx.x;
    const int cg  = bid % 3;                 // 0->gk,1->gv,2->lk
    const int rowBase = (bid / 3) * 64;
    const int t  = threadIdx.x;
    const int c4 = t & 31;
    const int r8 = t >> 5;

    __shared__ __align__(16) float wn_s[64][128];
    __shared__ __align__(16) float e_s[64][68];

    float acc[8][4];
#pragma unroll
    for (int j = 0; j < 8; ++j)
#pragma unroll
        for (int m = 0; m < 4; ++m) acc[j][m] = 0.f;

    for (int kh = 0; kh < 2; ++kh) {
#pragma unroll
        for (int i = 0; i < 8; ++i) {
            const int idx = t + 256 * i;
            const int kr = idx >> 5, cc = (idx & 31) * 4;
            *(float4*)&wn_s[kr][cc] =
                *(const float4*)&Wn[(size_t)(kh * 64 + kr) * 384 + 128 * cg + cc];
        }
#pragma unroll
        for (int i = 0; i < 4; ++i) {
            const int idx = t + 256 * i;
            const int rr = idx >> 4, kk4 = (idx & 15) * 4;
            *(float4*)&e_s[rr][kk4] =
                *(const float4*)&emb[(size_t)(rowBase + rr) * Dd + kh * 64 + kk4];
        }
        __syncthreads();

#pragma unroll
        for (int k4 = 0; k4 < 16; ++k4) {
            float4 er[8];
#pragma unroll
            for (int j = 0; j < 8; ++j)
                er[j] = *(const float4*)&e_s[8 * r8 + j][4 * k4];
#pragma unroll
            for (int m = 0; m < 4; ++m) {
                const float4 wv = *(const float4*)&wn_s[4 * k4 + m][4 * c4];
#pragma unroll
                for (int j = 0; j < 8; ++j) {
                    const float ev = (m == 0) ? er[j].x : (m == 1) ? er[j].y
                                   : (m == 2) ? er[j].z : er[j].w;
                    acc[j][0] = fmaf(ev, wv.x, acc[j][0]);
                    acc[j][1] = fmaf(ev, wv.y, acc[j][1]);
                    acc[j][2] = fmaf(ev, wv.z, acc[j][2]);
                    acc[j][3] = fmaf(ev, wv.w, acc[j][3]);
                }
            }
        }
        __syncthreads();
    }

    float* out = (cg == 0) ? gk : (cg == 1) ? gv : lk;
    const float scl = (cg == 0) ? QSCALE : (cg == 2) ? LSCALE : 1.0f;
#pragma unroll
    for (int j = 0; j < 8; ++j) {
        float4 v;
        v.x = acc[j][0] * scl; v.y = acc[j][1] * scl;
        v.z = acc[j][2] * scl; v.w = acc[j][3] * scl;
        *(float4*)&out[(size_t)(rowBase + 8 * r8 + j) * Dd + 4 * c4] = v;
    }
}

// ---------------- Kernel A2: ctx0 = mean(emb_b); fixedc = ctx0 @ W_fixed -----
__global__ __launch_bounds__(128) void ctxprep_kernel(
    const float* __restrict__ emb, const float* __restrict__ Wf,
    float* __restrict__ fixedc, float* __restrict__ ctx0row)
{
    const int b = blockIdx.x, d = threadIdx.x;
    __shared__ float c0[Dd];
    const float* e = emb + (size_t)b * Nn * Dd;
    float s = 0.f;
#pragma unroll 4
    for (int n = 0; n < Nn; ++n) s += e[n * Dd + d];
    s *= (1.0f / (float)Nn);
    c0[d] = s;
    ctx0row[(size_t)b * Dd + d] = s;
    __syncthreads();
    float f = 0.f;
#pragma unroll 8
    for (int k = 0; k < Dd; ++k) f = fmaf(c0[k], Wf[k * Dd + d], f);
    fixedc[(size_t)b * Dd + d] = f;
}

// ---------------- Kernel B: greedy decode, 2 blocks/CU ------------------------
__global__ __launch_bounds__(512, 4) void decode_kernel(
    const float* __restrict__ emb,
    const float* __restrict__ Wsp,  // W_step [D][D]
    const float* __restrict__ gk, const float* __restrict__ gv,
    const float* __restrict__ lk,
    const float* __restrict__ fixedc, const float* __restrict__ ctx0row,
    float* __restrict__ out_logp,   // [B][T][N]
    float* __restrict__ out_pi)     // [B][T] (as float)
{
    const int b    = blockIdx.x;
    const int t    = threadIdx.x;
    const int lane = t & 63;
    const int w    = t >> 6;      // wave id == head
    const int jq   = lane >> 2;   // 0..15 col within head
    const int kk   = lane & 3;    // quad slot: q k-chunk / glimpse n-slice

    __shared__ __align__(16) float sm2[8][256];   // wave-private attn p
    __shared__ __align__(16) float glim_s[Dd];
    __shared__ __align__(16) float logits_s[Nn];

    const float* embB = emb + (size_t)b * Nn * Dd;
    const float* gkB  = gk  + (size_t)b * Nn * Dd;
    const float* gvB  = gv  + (size_t)b * Nn * Dd;
    const float* lkB  = lk  + (size_t)b * Nn * Dd;

    // ---------------- persistent registers ----------------
    float4 gk0[4], gk1[4], gk2[4], gk3[4];  // prescaled K frags (head w, n=lane+64k)
    float  wsa[32];                          // W_step[32kk+j][16w+jq]
    float  gva[52];                          // V rows 52kk..+51 (clamp), col 16w+jq
    float  lka[64];                          // prescaled logit-K (t<400: n=t>>1, half t&1)
    float  cb0, cb1, cb2, cb3;               // fixedc-fold compat bias per n-chunk

    {
        const float4* s0 = (const float4*)(gkB + (size_t)(lane      ) * Dd + 16 * w);
        const float4* s1 = (const float4*)(gkB + (size_t)(lane +  64) * Dd + 16 * w);
        const float4* s2 = (const float4*)(gkB + (size_t)(lane + 128) * Dd + 16 * w);
        const int n3 = (lane < 8) ? lane + 192 : 199;
        const float4* s3 = (const float4*)(gkB + (size_t)n3 * Dd + 16 * w);
#pragma unroll
        for (int i = 0; i < 4; ++i) { gk0[i]=s0[i]; gk1[i]=s1[i]; gk2[i]=s2[i]; gk3[i]=s3[i]; }
    }
#pragma unroll
    for (int j = 0; j < 32; ++j)
        wsa[j] = Wsp[(size_t)(32 * kk + j) * Dd + 16 * w + jq];
#pragma unroll
    for (int k = 0; k < 52; ++k) {
        int r = 52 * kk + k; r = r < 200 ? r : 199;
        gva[k] = gvB[(size_t)r * Dd + 16 * w + jq];
    }
    if (t < 400) {
        const float4* src = (const float4*)(lkB + (size_t)(t >> 1) * Dd + (t & 1) * 64);
#pragma unroll
        for (int i = 0; i < 16; ++i) *(float4*)&lka[4 * i] = src[i];
    } else {
#pragma unroll
        for (int i = 0; i < 64; ++i) lka[i] = 0.f;
    }
    {   // cbias: dot16(fixedc_headslice, prescaled gk)
        float4 fcf[4];
        const float4* fcp = (const float4*)(fixedc + (size_t)b * Dd + 16 * w);
#pragma unroll
        for (int i = 0; i < 4; ++i) fcf[i] = fcp[i];
        cb0 = dot16pk(gk0, fcf);
        cb1 = dot16pk(gk1, fcf);
        cb2 = dot16pk(gk2, fcf);
        cb3 = dot16pk(gk3, fcf);
    }

    // ================= decode loop: 2 barriers/step =================
    unsigned long long vis0 = 0, vis1 = 0, vis2 = 0, vis3 = 0;
    int sel_prev = -1;

    for (int step = 0; step < Nn; ++step) {
        // q GEMV: ctx row (global, broadcast) x persistent W_step regs
        const float* rowp = (step == 0) ? (ctx0row + (size_t)b * Dd)
                                        : (embB + (size_t)sel_prev * Dd);
        {
            const float4* c4 = (const float4*)(rowp + 32 * kk);
            const v2f* wsv = (const v2f*)wsa;
            v2f a0 = {0.f, 0.f}, a1 = {0.f, 0.f};
#pragma unroll
            for (int i = 0; i < 8; i += 2) {
                const float4 ca = c4[i], cb = c4[i + 1];
                a0 = pkfma((v2f){ca.x, ca.y}, wsv[2 * i + 0], a0);
                a1 = pkfma((v2f){ca.z, ca.w}, wsv[2 * i + 1], a1);
                a0 = pkfma((v2f){cb.x, cb.y}, wsv[2 * i + 2], a0);
                a1 = pkfma((v2f){cb.z, cb.w}, wsv[2 * i + 3], a1);
            }
            const v2f a = a0 + a1;
            float s = a.x + a.y;
            s += __shfl_xor(s, 1);
            s += __shfl_xor(s, 2);        // all 4 quad lanes: qraw[jq]
            // broadcast q to whole wave
            float4 qf[4];
            qf[0].x = rdlane(s, 0);  qf[0].y = rdlane(s, 4);
            qf[0].z = rdlane(s, 8);  qf[0].w = rdlane(s, 12);
            qf[1].x = rdlane(s, 16); qf[1].y = rdlane(s, 20);
            qf[1].z = rdlane(s, 24); qf[1].w = rdlane(s, 28);
            qf[2].x = rdlane(s, 32); qf[2].y = rdlane(s, 36);
            qf[2].z = rdlane(s, 40); qf[2].w = rdlane(s, 44);
            qf[3].x = rdlane(s, 48); qf[3].y = rdlane(s, 52);
            qf[3].z = rdlane(s, 56); qf[3].w = rdlane(s, 60);

            // compat (log2 domain: gk prescaled, fixedc via cbias) -> p
            float x0 = dot16pk(gk0, qf) + cb0;
            float x1 = dot16pk(gk1, qf) + cb1;
            float x2 = dot16pk(gk2, qf) + cb2;
            float x3 = dot16pk(gk3, qf) + cb3;
            x0 = ((vis0 >> lane) & 1ull) ? -1e30f : x0;
            x1 = ((vis1 >> lane) & 1ull) ? -1e30f : x1;
            x2 = ((vis2 >> lane) & 1ull) ? -1e30f : x2;
            x3 = (lane < 8 && !((vis3 >> lane) & 1ull)) ? x3 : -1e30f;
            const float p0 = exp2f(x0), p1 = exp2f(x1), p2 = exp2f(x2), p3 = exp2f(x3);
            float* prow = &sm2[w][0];
            prow[lane      ] = p0;
            prow[lane +  64] = p1;
            prow[lane + 128] = p2;
            prow[lane + 192] = p3;        // n in [200,256): zeros
            float ps = (p0 + p1) + (p2 + p3);
#pragma unroll
            for (int off = 1; off < 64; off <<= 1) ps += __shfl_xor(ps, off);
            const float invps = fast_rcp(ps);

            // glimpse (wave-private): col 16w+jq, n-slice [52kk, 52kk+52)
            const v2f* av = (const v2f*)(&sm2[w][52 * kk]);
            const v2f* gvv = (const v2f*)gva;
            v2f g0 = {0.f, 0.f}, g1 = {0.f, 0.f};
#pragma unroll
            for (int k2 = 0; k2 < 26; k2 += 2) {
                g0 = pkfma(av[k2], gvv[k2], g0);
                g1 = pkfma(av[k2 + 1], gvv[k2 + 1], g1);
            }
            const v2f gt = g0 + g1;
            float gsum = gt.x + gt.y;
            gsum += __shfl_xor(gsum, 1);
            gsum += __shfl_xor(gsum, 2);
            if (kk == 0) glim_s[16 * w + jq] = gsum * invps;
        }
        __syncthreads();                                   // B1: glim ready

        // logits: t<400, n=t>>1, half jh=t&1 -> pk dot64 + pair shuffle
        if (t < 400) {
            const int n = t >> 1, jh = t & 1;
            const v2f* gl = (const v2f*)(glim_s + 64 * jh);
            const v2f* lv = (const v2f*)lka;
            v2f a0 = {0.f,0.f}, a1 = {0.f,0.f}, a2 = {0.f,0.f}, a3 = {0.f,0.f};
#pragma unroll
            for (int i = 0; i < 32; i += 4) {
                a0 = pkfma(lv[i + 0], gl[i + 0], a0);
                a1 = pkfma(lv[i + 1], gl[i + 1], a1);
                a2 = pkfma(lv[i + 2], gl[i + 2], a2);
                a3 = pkfma(lv[i + 3], gl[i + 3], a3);
            }
            const v2f at = (a0 + a1) + (a2 + a3);
            float sl = at.x + at.y;
            sl += __shfl_xor(sl, 1);
            if (jh == 0) {
                const float u = exp2f(sl);                  // e^{2x}, lk prescaled
                const float v = TANH_CLIP - 2.0f * TANH_CLIP * fast_rcp(u + 1.0f);
                const int w2 = n >> 6, bit = n & 63;
                const unsigned long long mw = (w2 == 0) ? vis0 : (w2 == 1) ? vis1
                                            : (w2 == 2) ? vis2 : vis3;
                logits_s[n] = ((mw >> bit) & 1ull) ? NEG_INF : v;
            }
        }
        __syncthreads();                                   // B2: logits ready

        // argmax + lse, redundant per wave (ballot; fixed max = 10)
        const float v0 = logits_s[lane], v1 = logits_s[lane + 64], v2 = logits_s[lane + 128];
        const float v3 = (lane < 8) ? logits_s[lane + 192] : -INFINITY;
        float mx = fmaxf(fmaxf(v0, v1), fmaxf(v2, v3));
        float e0 = exp2f((v0 - 10.f) * LOG2E) + exp2f((v1 - 10.f) * LOG2E)
                 + exp2f((v2 - 10.f) * LOG2E)
                 + ((lane < 8) ? exp2f((v3 - 10.f) * LOG2E) : 0.f);
#pragma unroll
        for (int off = 1; off < 64; off <<= 1) {
            mx = fmaxf(mx, __shfl_xor(mx, off));
            e0 += __shfl_xor(e0, off);
        }
        const unsigned long long b0 = __ballot(v0 == mx);
        const unsigned long long b1 = __ballot(v1 == mx);
        const unsigned long long b2 = __ballot(v2 == mx);
        const unsigned long long b3 = __ballot(v3 == mx);
        const int sel = b0 ? __builtin_ctzll(b0)
                      : b1 ? 64  + __builtin_ctzll(b1)
                      : b2 ? 128 + __builtin_ctzll(b2)
                      :      192 + __builtin_ctzll(b3);
        const float lse = log2f(e0) * LN2 + 10.f;

        // outputs + state
        if (t < 50) {
            float4 lv4 = *(const float4*)&logits_s[4 * t];
            lv4.x -= lse; lv4.y -= lse; lv4.z -= lse; lv4.w -= lse;
            *(float4*)&out_logp[((size_t)b * Nn + step) * Nn + 4 * t] = lv4;
        }
        if (t == 0) out_pi[(size_t)b * Nn + step] = (float)sel;
        const unsigned long long sbit = 1ull << (sel & 63);
        const int sw = sel >> 6;
        vis0 |= (sw == 0) ? sbit : 0ull;
        vis1 |= (sw == 1) ? sbit : 0ull;
        vis2 |= (sw == 2) ? sbit : 0ull;
        vis3 |= (sw == 3) ? sbit : 0ull;
        sel_prev = sel;
    }
}

// ----------------------------------------------------------------------------
extern "C" void kernel_launch(void* const* d_in, const int* in_sizes, int n_in,
                              void* d_out, int out_size, void* d_ws, size_t ws_size,
                              hipStream_t stream) {
    (void)in_sizes; (void)n_in; (void)out_size; (void)ws_size;
    const float* emb = (const float*)d_in[0];   // [B,N,D]
    const float* Wn  = (const float*)d_in[1];   // [D,3D]
    const float* Wf  = (const float*)d_in[2];   // [D,D]
    const float* Wsp = (const float*)d_in[3];   // [D,D]

    const size_t BND = (size_t)Bsz * Nn * Dd;
    float* gk      = (float*)d_ws;              // prescaled by QSCALE
    float* gv      = gk + BND;
    float* lk      = gv + BND;                  // prescaled by LSCALE
    float* fixedc  = lk + BND;                  // [B][D]
    float* ctx0row = fixedc + (size_t)Bsz * Dd; // [B][D]

    float* out_logp = (float*)d_out;                       // [B,T,N]
    float* out_pi   = out_logp + (size_t)Bsz * Nn * Nn;    // [B,T] as float

    proj_kernel<<<(Bsz * Nn / 64) * 3, 256, 0, stream>>>(emb, Wn, gk, gv, lk);
    ctxprep_kernel<<<Bsz, 128, 0, stream>>>(emb, Wf, fixedc, ctx0row);
    decode_kernel<<<Bsz, 512, 0, stream>>>(emb, Wsp, gk, gv, lk, fixedc, ctx0row,
                                           out_logp, out_pi);
}

// Round 7
// 1005.036 us; speedup vs baseline: 4.5439x; 4.5439x over previous
//
#include <hip/hip_runtime.h>
#include <math.h>

// GlimpseDecoder: B=512, N=T=200, D=128, H=8, dk=16
// R7: one barrier/step. Wave-private q/compat/softmax/glimpse/partial-logits
// (wave = head); cross-wave only for the 8-way logit partial sum (smp, double
// buffered). Final logits, argmax, lse all in registers. Full on-chip
// residency: qall in LDS, gk/gv/lk slices in regs (launch_bounds(512,2)).

#define Bsz 512
#define Nn  200
#define Dd  128
#define TANH_CLIP 10.0f
#define NEG_INF  -1e9f
#define LOG2E 1.4426950408889634f
#define LN2   0.6931471805599453f
#define QSCALE (0.25f * LOG2E)                       // 1/sqrt(16) * log2(e)
#define LSCALE (0.08838834764831845f * 2.0f * LOG2E) // 1/sqrt(128)*2*log2(e)

typedef float v2f __attribute__((ext_vector_type(2)));

__device__ __forceinline__ v2f pkfma(v2f a, v2f b, v2f c) {
    return __builtin_elementwise_fma(a, b, c);
}
__device__ __forceinline__ float fast_rcp(float x) {
    return __builtin_amdgcn_rcpf(x);
}
// dot of 16 floats via packed fma (two chains) + horizontal add
__device__ __forceinline__ float dot16pk(const float4* g4, const float4* q4) {
    const v2f* g = (const v2f*)g4;
    const v2f* q = (const v2f*)q4;
    v2f a0 = g[0] * q[0];
    v2f a1 = g[1] * q[1];
    a0 = pkfma(g[2], q[2], a0);
    a1 = pkfma(g[3], q[3], a1);
    a0 = pkfma(g[4], q[4], a0);
    a1 = pkfma(g[5], q[5], a1);
    a0 = pkfma(g[6], q[6], a0);
    a1 = pkfma(g[7], q[7], a1);
    const v2f a = a0 + a1;
    return a.x + a.y;
}

// ---------------- Kernel A: tiled proj = emb @ W_node -> gk*QS, gv, lk*LS ----
__global__ __launch_bounds__(256, 3) void proj_kernel(
    const float* __restrict__ emb, const float* __restrict__ Wn,
    float* __restrict__ gk, float* __restrict__ gv, float* __restrict__ lk)
{
    const int bid = blockIdx.x;
    const int cg  = bid % 3;                 // 0->gk,1->gv,2->lk
    const int rowBase = (bid / 3) * 64;
    const int t  = threadIdx.x;
    const int c4 = t & 31;
    const int r8 = t >> 5;

    __shared__ __align__(16) float wn_s[64][128];
    __shared__ __align__(16) float e_s[64][68];

    float acc[8][4];
#pragma unroll
    for (int j = 0; j < 8; ++j)
#pragma unroll
        for (int m = 0; m < 4; ++m) acc[j][m] = 0.f;

    for (int kh = 0; kh < 2; ++kh) {
#pragma unroll
        for (int i = 0; i < 8; ++i) {
            const int idx = t + 256 * i;
            const int kr = idx >> 5, cc = (idx & 31) * 4;
            *(float4*)&wn_s[kr][cc] =
                *(const float4*)&Wn[(size_t)(kh * 64 + kr) * 384 + 128 * cg + cc];
        }
#pragma unroll
        for (int i = 0; i < 4; ++i) {
            const int idx = t + 256 * i;
            const int rr = idx >> 4, kk4 = (idx & 15) * 4;
            *(float4*)&e_s[rr][kk4] =
                *(const float4*)&emb[(size_t)(rowBase + rr) * Dd + kh * 64 + kk4];
        }
        __syncthreads();

#pragma unroll
        for (int k4 = 0; k4 < 16; ++k4) {
            float4 er[8];
#pragma unroll
            for (int j = 0; j < 8; ++j)
                er[j] = *(const float4*)&e_s[8 * r8 + j][4 * k4];
#pragma unroll
            for (int m = 0; m < 4; ++m) {
                const float4 wv = *(const float4*)&wn_s[4 * k4 + m][4 * c4];
#pragma unroll
                for (int j = 0; j < 8; ++j) {
                    const float ev = (m == 0) ? er[j].x : (m == 1) ? er[j].y
                                   : (m == 2) ? er[j].z : er[j].w;
                    acc[j][0] = fmaf(ev, wv.x, acc[j][0]);
                    acc[j][1] = fmaf(ev, wv.y, acc[j][1]);
                    acc[j][2] = fmaf(ev, wv.z, acc[j][2]);
                    acc[j][3] = fmaf(ev, wv.w, acc[j][3]);
                }
            }
        }
        __syncthreads();
    }

    float* out = (cg == 0) ? gk : (cg == 1) ? gv : lk;
    const float scl = (cg == 0) ? QSCALE : (cg == 2) ? LSCALE : 1.0f;
#pragma unroll
    for (int j = 0; j < 8; ++j) {
        float4 v;
        v.x = acc[j][0] * scl; v.y = acc[j][1] * scl;
        v.z = acc[j][2] * scl; v.w = acc[j][3] * scl;
        *(float4*)&out[(size_t)(rowBase + 8 * r8 + j) * Dd + 4 * c4] = v;
    }
}

// ---------------- Kernel B: greedy decode, 1 barrier/step ---------------------
__global__ __launch_bounds__(512, 2) void decode_kernel(
    const float* __restrict__ emb,
    const float* __restrict__ Wf,   // W_fixed [D][D]
    const float* __restrict__ Wsp,  // W_step  [D][D]
    const float* __restrict__ gk, const float* __restrict__ gv,
    const float* __restrict__ lk,
    float* __restrict__ out_logp,   // [B][T][N]
    float* __restrict__ out_pi)     // [B][T] (as float)
{
    const int b    = blockIdx.x;
    const int t    = threadIdx.x;
    const int lane = t & 63;
    const int w    = t >> 6;      // wave id == head
    const int g    = t >> 7;      // prologue group 0..3
    const int d    = t & 127;     // prologue col
    const int jq   = lane >> 2;   // col within head (0..15)
    const int kk   = lane & 3;    // quad slot: glimpse n-slice

    __shared__ __align__(16) float qall_s[201 * Dd];   // 100.5 KB raw q-base
    __shared__ __align__(16) float wchunk_s[16][Dd];   // 8 KB
    __shared__ __align__(16) float sm2[8][256];        // 8 KB wave-private p
    __shared__ __align__(16) float glimbc[8][16];      // 0.5 KB
    __shared__             float smp[2][256][9];       // 18 KB logit partials
    __shared__ __align__(16) float red[4][Dd];         // 2 KB
    __shared__ __align__(16) float ctx0_s[Dd];
    __shared__ __align__(16) float fixedc_s[Dd];       // RAW

    const float* embB = emb + (size_t)b * Nn * Dd;
    const float* gkB  = gk  + (size_t)b * Nn * Dd;
    const float* gvB  = gv  + (size_t)b * Nn * Dd;
    const float* lkB  = lk  + (size_t)b * Nn * Dd;

    // ================= prologue =================
    {   // emb -> qall_s rows 0..199
        const float4* e4  = (const float4*)embB;
        float4*       es4 = (float4*)qall_s;
#pragma unroll
        for (int it = 0; it < 12; ++it) es4[t + 512 * it] = e4[t + 512 * it];
        if (t < 256) es4[t + 6144] = e4[t + 6144];
    }
    __syncthreads();

    // ctx0 = mean over 200 rows
    {
        float s = 0.f;
#pragma unroll
        for (int k = 0; k < 50; ++k) s += qall_s[(50 * g + k) * Dd + d];
        red[g][d] = s;
    }
    __syncthreads();
    if (t < 128) ctx0_s[t] = (red[0][t] + red[1][t] + red[2][t] + red[3][t]) * (1.0f / 200.0f);
    __syncthreads();

    // fixedc (RAW) = ctx0 @ W_fixed; append ctx0 as row 200
    {
        float s = 0.f;
#pragma unroll
        for (int j = 0; j < 32; ++j)
            s = fmaf(ctx0_s[32 * g + j], Wf[(32 * g + j) * Dd + d], s);
        red[g][d] = s;
    }
    __syncthreads();
    if (t < 128) {
        fixedc_s[t] = red[0][t] + red[1][t] + red[2][t] + red[3][t];
        qall_s[200 * Dd + t] = ctx0_s[t];
    }
    __syncthreads();

    // qall GEMM (RAW): rows 52g..52g+51 (<=200), col d; k staged in 8 chunks
    float qr[52];
#pragma unroll
    for (int i = 0; i < 52; ++i) qr[i] = 0.f;

    for (int kc = 0; kc < 8; ++kc) {
        {
            const int kr = t >> 5, cc = (t & 31) * 4;
            *(float4*)&wchunk_s[kr][cc] =
                *(const float4*)&Wsp[(size_t)(16 * kc + kr) * Dd + cc];
        }
        __syncthreads();
#pragma unroll
        for (int i = 0; i < 52; ++i) {
            const int r = 52 * g + i;
            if (r < 201) {
#pragma unroll
                for (int j4 = 0; j4 < 4; ++j4) {
                    const float4 ev = *(const float4*)&qall_s[r * Dd + 16 * kc + 4 * j4];
                    qr[i] = fmaf(ev.x, wchunk_s[4 * j4 + 0][d], qr[i]);
                    qr[i] = fmaf(ev.y, wchunk_s[4 * j4 + 1][d], qr[i]);
                    qr[i] = fmaf(ev.z, wchunk_s[4 * j4 + 2][d], qr[i]);
                    qr[i] = fmaf(ev.w, wchunk_s[4 * j4 + 3][d], qr[i]);
                }
            }
        }
        __syncthreads();
    }
#pragma unroll
    for (int i = 0; i < 52; ++i) {
        const int r = 52 * g + i;
        if (r < 201) qall_s[r * Dd + d] = qr[i];      // RAW q-base
    }
    __syncthreads();

    // ---------------- persistent registers ----------------
    float4 gk0[4], gk1[4], gk2[4], gk3[4];  // prescaled K frags: n = lane+64k
    float4 lk0[4], lk1[4], lk2[4], lk3[4];  // prescaled logit-K frags, same n-map
    float  gva[52];                          // V rows 52kk..+51 (clamp), col 16w+jq
    float  cb0, cb1, cb2, cb3;               // compat bias: gk_pre . fixedc(raw)
    {
        const float4* s0 = (const float4*)(gkB + (size_t)(lane      ) * Dd + 16 * w);
        const float4* s1 = (const float4*)(gkB + (size_t)(lane +  64) * Dd + 16 * w);
        const float4* s2 = (const float4*)(gkB + (size_t)(lane + 128) * Dd + 16 * w);
        const int n3 = (lane < 8) ? lane + 192 : 199;
        const float4* s3 = (const float4*)(gkB + (size_t)n3 * Dd + 16 * w);
#pragma unroll
        for (int i = 0; i < 4; ++i) { gk0[i]=s0[i]; gk1[i]=s1[i]; gk2[i]=s2[i]; gk3[i]=s3[i]; }
        const float4* l0 = (const float4*)(lkB + (size_t)(lane      ) * Dd + 16 * w);
        const float4* l1 = (const float4*)(lkB + (size_t)(lane +  64) * Dd + 16 * w);
        const float4* l2 = (const float4*)(lkB + (size_t)(lane + 128) * Dd + 16 * w);
        const float4* l3 = (const float4*)(lkB + (size_t)n3 * Dd + 16 * w);
#pragma unroll
        for (int i = 0; i < 4; ++i) { lk0[i]=l0[i]; lk1[i]=l1[i]; lk2[i]=l2[i]; lk3[i]=l3[i]; }
    }
#pragma unroll
    for (int k = 0; k < 52; ++k) {
        int r = 52 * kk + k; r = r < 200 ? r : 199;
        gva[k] = gvB[(size_t)r * Dd + 16 * w + jq];
    }
    {
        float4 fcf[4];
        const float4* fcp = (const float4*)(fixedc_s + 16 * w);
#pragma unroll
        for (int i = 0; i < 4; ++i) fcf[i] = fcp[i];
        cb0 = dot16pk(gk0, fcf);
        cb1 = dot16pk(gk1, fcf);
        cb2 = dot16pk(gk2, fcf);
        cb3 = dot16pk(gk3, fcf);
    }

    // ================= decode loop: 1 barrier/step =================
    unsigned long long vis0 = 0, vis1 = 0, vis2 = 0, vis3 = 0;
    int sel_prev = 200;     // row 200 = ctx0 q-base
    int par = 0;

    for (int step = 0; step < Nn; ++step) {
        // q (raw) for head w: 64B broadcast read from LDS
        float4 qf[4];
        {
            const float4* qp = (const float4*)(qall_s + sel_prev * Dd + 16 * w);
            qf[0] = qp[0]; qf[1] = qp[1]; qf[2] = qp[2]; qf[3] = qp[3];
        }

        // compat (log2 domain) -> masked -> p
        float x0 = dot16pk(gk0, qf) + cb0;
        float x1 = dot16pk(gk1, qf) + cb1;
        float x2 = dot16pk(gk2, qf) + cb2;
        float x3 = dot16pk(gk3, qf) + cb3;
        x0 = ((vis0 >> lane) & 1ull) ? -1e30f : x0;
        x1 = ((vis1 >> lane) & 1ull) ? -1e30f : x1;
        x2 = ((vis2 >> lane) & 1ull) ? -1e30f : x2;
        x3 = (lane < 8 && !((vis3 >> lane) & 1ull)) ? x3 : -1e30f;
        const float p0 = exp2f(x0), p1 = exp2f(x1), p2 = exp2f(x2), p3 = exp2f(x3);
        {
            float* prow = &sm2[w][0];
            prow[lane      ] = p0;
            prow[lane +  64] = p1;
            prow[lane + 128] = p2;
            prow[lane + 192] = p3;   // slots 200..255 get zeros (masked lanes)
        }
        float ps = (p0 + p1) + (p2 + p3);
#pragma unroll
        for (int off = 1; off < 64; off <<= 1) ps += __shfl_xor(ps, off);
        const float invps = fast_rcp(ps);

        // glimpse (wave-private; DS ops in-order within wave)
        {
            const v2f* av  = (const v2f*)(&sm2[w][52 * kk]);
            const v2f* gvv = (const v2f*)gva;
            v2f g0 = {0.f, 0.f}, g1 = {0.f, 0.f};
#pragma unroll
            for (int k2 = 0; k2 < 26; k2 += 2) {
                g0 = pkfma(av[k2],     gvv[k2],     g0);
                g1 = pkfma(av[k2 + 1], gvv[k2 + 1], g1);
            }
            const v2f gt = g0 + g1;
            float gsum = gt.x + gt.y;
            gsum += __shfl_xor(gsum, 1);
            gsum += __shfl_xor(gsum, 2);
            if (kk == 0) glimbc[w][jq] = gsum * invps;
        }
        // read own-head glimpse slice (wave-private)
        float4 gw[4];
        {
            const float4* gbp = (const float4*)&glimbc[w][0];
            gw[0] = gbp[0]; gw[1] = gbp[1]; gw[2] = gbp[2]; gw[3] = gbp[3];
        }

        // partial logits for own head, own n's -> smp
        smp[par][lane      ][w] = dot16pk(lk0, gw);
        smp[par][lane +  64][w] = dot16pk(lk1, gw);
        smp[par][lane + 128][w] = dot16pk(lk2, gw);
        smp[par][lane + 192][w] = dot16pk(lk3, gw);
        __syncthreads();                                   // THE barrier

        // gather 8 partials per n, finish tanh+mask in regs
        float sl0 = 0.f, sl1 = 0.f, sl2 = 0.f, sl3 = 0.f;
#pragma unroll
        for (int w2 = 0; w2 < 8; ++w2) {
            sl0 += smp[par][lane      ][w2];
            sl1 += smp[par][lane +  64][w2];
            sl2 += smp[par][lane + 128][w2];
            sl3 += smp[par][lane + 192][w2];
        }
        const float u0 = exp2f(sl0), u1 = exp2f(sl1), u2 = exp2f(sl2), u3 = exp2f(sl3);
        float l0 = TANH_CLIP - 2.0f * TANH_CLIP * fast_rcp(u0 + 1.0f);
        float l1 = TANH_CLIP - 2.0f * TANH_CLIP * fast_rcp(u1 + 1.0f);
        float l2 = TANH_CLIP - 2.0f * TANH_CLIP * fast_rcp(u2 + 1.0f);
        float l3 = TANH_CLIP - 2.0f * TANH_CLIP * fast_rcp(u3 + 1.0f);
        l0 = ((vis0 >> lane) & 1ull) ? NEG_INF : l0;
        l1 = ((vis1 >> lane) & 1ull) ? NEG_INF : l1;
        l2 = ((vis2 >> lane) & 1ull) ? NEG_INF : l2;
        l3 = (lane < 8 && !((vis3 >> lane) & 1ull)) ? l3 : NEG_INF;

        // argmax (ballot) + lse (fixed max = 10), dual shuffle chains
        float mx = fmaxf(fmaxf(l0, l1), fmaxf(l2, l3));
        float e0 = exp2f((l0 - 10.f) * LOG2E) + exp2f((l1 - 10.f) * LOG2E)
                 + exp2f((l2 - 10.f) * LOG2E) + exp2f((l3 - 10.f) * LOG2E);
#pragma unroll
        for (int off = 1; off < 64; off <<= 1) {
            mx = fmaxf(mx, __shfl_xor(mx, off));
            e0 += __shfl_xor(e0, off);
        }
        const unsigned long long b0 = __ballot(l0 == mx);
        const unsigned long long b1 = __ballot(l1 == mx);
        const unsigned long long b2 = __ballot(l2 == mx);
        const unsigned long long b3 = __ballot(l3 == mx);
        const int sel = b0 ? __builtin_ctzll(b0)
                      : b1 ? 64  + __builtin_ctzll(b1)
                      : b2 ? 128 + __builtin_ctzll(b2)
                      :      192 + __builtin_ctzll(b3);
        const float lse = log2f(e0) * LN2 + 10.f;

        // outputs (wave 0 only; coalesced 4B stores) + state
        if (w == 0) {
            float* orow = out_logp + ((size_t)b * Nn + step) * Nn;
            orow[lane      ] = l0 - lse;
            orow[lane +  64] = l1 - lse;
            orow[lane + 128] = l2 - lse;
            if (lane < 8) orow[lane + 192] = l3 - lse;
            if (lane == 0) out_pi[(size_t)b * Nn + step] = (float)sel;
        }
        const unsigned long long sbit = 1ull << (sel & 63);
        const int sw = sel >> 6;
        vis0 |= (sw == 0) ? sbit : 0ull;
        vis1 |= (sw == 1) ? sbit : 0ull;
        vis2 |= (sw == 2) ? sbit : 0ull;
        vis3 |= (sw == 3) ? sbit : 0ull;
        sel_prev = sel;
        par ^= 1;
    }
}

// ----------------------------------------------------------------------------
extern "C" void kernel_launch(void* const* d_in, const int* in_sizes, int n_in,
                              void* d_out, int out_size, void* d_ws, size_t ws_size,
                              hipStream_t stream) {
    (void)in_sizes; (void)n_in; (void)out_size; (void)ws_size;
    const float* emb = (const float*)d_in[0];   // [B,N,D]
    const float* Wn  = (const float*)d_in[1];   // [D,3D]
    const float* Wf  = (const float*)d_in[2];   // [D,D]
    const float* Wsp = (const float*)d_in[3];   // [D,D]

    const size_t BND = (size_t)Bsz * Nn * Dd;
    float* gk = (float*)d_ws;                   // prescaled by QSCALE
    float* gv = gk + BND;
    float* lk = gv + BND;                       // prescaled by LSCALE

    float* out_logp = (float*)d_out;                       // [B,T,N]
    float* out_pi   = out_logp + (size_t)Bsz * Nn * Nn;    // [B,T] as float

    proj_kernel<<<(Bsz * Nn / 64) * 3, 256, 0, stream>>>(emb, Wn, gk, gv, lk);
    decode_kernel<<<Bsz, 512, 0, stream>>>(emb, Wf, Wsp, gk, gv, lk,
                                           out_logp, out_pi);
}